// Round 1
// baseline (152.659 us; speedup 1.0000x reference)
//
#include <hip/hip_runtime.h>
#include <hip/hip_bf16.h>

#define LL 128
#define DD 256
#define PP 1024
#define TU_C 86400
#define TB_C 3600
#define NEGF -4294967296.0f   // float(-2**32+1) rounds to -2^32

__device__ __forceinline__ float wredSum(float v) {
#pragma unroll
  for (int o = 32; o; o >>= 1) v += __shfl_xor(v, o);
  return v;
}
__device__ __forceinline__ float wredMax(float v) {
#pragma unroll
  for (int o = 32; o; o >>= 1) v = fmaxf(v, __shfl_xor(v, o));
  return v;
}
__device__ __forceinline__ float dot4f(const float4 a, const float4 b) {
  return a.x * b.x + a.y * b.y + a.z * b.z + a.w * b.w;
}

// ---------------------------------------------------------------------------
// Kernel 1: Q/K/V projections. grid (32 row-tiles, 3 matrices), 256 threads.
// out[r, t] = sum_e src[r,e] * w[t,e] + bias[t]   (x @ W^T + b)
// ---------------------------------------------------------------------------
__global__ __launch_bounds__(256) void k_qkv(
    const float* __restrict__ src,
    const float* __restrict__ wq, const float* __restrict__ bq,
    const float* __restrict__ wk, const float* __restrict__ bk,
    const float* __restrict__ wv, const float* __restrict__ bv,
    float* __restrict__ Q, float* __restrict__ K, float* __restrict__ V)
{
  __shared__ float xs[16][DD];
  const int t = threadIdx.x;
  const int r0 = blockIdx.x * 16;
  const float* w; const float* bi; float* o;
  if (blockIdx.y == 0)      { w = wq; bi = bq; o = Q; }
  else if (blockIdx.y == 1) { w = wk; bi = bk; o = K; }
  else                      { w = wv; bi = bv; o = V; }
  for (int i = t; i < 16 * DD; i += 256) xs[i >> 8][i & 255] = src[r0 * DD + i];
  __syncthreads();
  float acc[16];
  const float bv_ = bi[t];
#pragma unroll
  for (int r = 0; r < 16; ++r) acc[r] = bv_;
  for (int e = 0; e < DD; e += 4) {
    const float4 w4 = *(const float4*)(w + t * DD + e);
#pragma unroll
    for (int r = 0; r < 16; ++r) acc[r] += dot4f(w4, *(const float4*)&xs[r][e]);
  }
#pragma unroll
  for (int r = 0; r < 16; ++r) o[(r0 + r) * DD + t] = acc[r];
}

// ---------------------------------------------------------------------------
// Kernel 2: fused attention row: scores (+time-emb via qh/qd lookup), softmax,
// aw@V + histogram-weighted embedding sums, residual, LayerNorm.
// grid 512 = (b,j), 256 threads.
// ---------------------------------------------------------------------------
__global__ __launch_bounds__(256) void k_attn(
    const float* __restrict__ Q, const float* __restrict__ Km, const float* __restrict__ Vm,
    const float* __restrict__ src,
    const float* __restrict__ hour_emb, const float* __restrict__ day_emb,
    const int* __restrict__ seq_lens, const int* __restrict__ ts_g,
    const float* __restrict__ g11, const float* __restrict__ b11,
    float* __restrict__ X)
{
  const int b = blockIdx.x >> 7;
  const int j = blockIdx.x & (LL - 1);
  const int t = threadIdx.x;
  __shared__ float qrow[DD];
  __shared__ float sc[LL];
  __shared__ float qhd[34];   // qh[0..25], qd[26..33]
  __shared__ float whd[34];   // weighted histograms
  __shared__ float red[8];
  qrow[t] = Q[(b * LL + j) * DD + t];
  if (t < 34) whd[t] = 0.f;
  __syncthreads();
  // per-row dot of Q with each of the 26 hour + 8 day embedding rows
  if (t < 34) {
    const float* emb = (t < 26) ? (hour_emb + t * DD) : (day_emb + (t - 26) * DD);
    float a = 0.f;
    for (int e = 0; e < DD; e += 4)
      a += dot4f(*(const float4*)&qrow[e], *(const float4*)(emb + e));
    qhd[t] = a;
  }
  const int len = seq_lens[b];
  const int* ts = ts_g + b * LL;
  const int tj = ts[j];
  float kdot = 0.f;
  int hidx = 0, didx = 0;
  bool valid = false;
  if (t < LL) {
    const float* kr = Km + (b * LL + t) * DD;
    for (int e = 0; e < DD; e += 4)
      kdot += dot4f(*(const float4*)&qrow[e], *(const float4*)(kr + e));
    valid = (j < len) && (t <= j);
    if (valid) {
      const int diff = tj - ts[t];                       // >= 0 (ts sorted, t<=j)
      hidx = (j == b) ? 1 : ((diff % TU_C) / TB_C + 2);  // faithful j==b bug
      didx = min(diff / TU_C + 1, 7);
    }
  }
  __syncthreads();  // qhd ready
  float s = NEGF;
  if (valid) s = (kdot + qhd[hidx] + qhd[26 + didx]) * 0.0625f;  // /sqrt(256)
  // softmax over k=0..127 (NEG rows -> uniform 1/128, matching reference)
  float mv = (t < LL) ? s : -3.4e38f;
  mv = wredMax(mv);
  if ((t & 63) == 0) red[t >> 6] = mv;
  __syncthreads();
  const float m = fmaxf(fmaxf(red[0], red[1]), fmaxf(red[2], red[3]));
  const float p = (t < LL) ? expf(s - m) : 0.f;
  const float svr = wredSum(p);
  if ((t & 63) == 0) red[4 + (t >> 6)] = svr;
  __syncthreads();
  const float Z = red[4] + red[5] + red[6] + red[7];
  if (t < LL) {
    const float aw = p / Z;
    sc[t] = aw;
    atomicAdd(&whd[hidx], aw);       // idx 0 -> zero embedding row: harmless
    atomicAdd(&whd[26 + didx], aw);
  }
  __syncthreads();
  // x[d] = sum_k aw[k] V[k,d] + sum_i wh[i] hour_emb[i,d] + sum_i wd[i] day_emb[i,d]
  const float* vb = Vm + b * LL * DD;
  float xv = 0.f;
  for (int k = 0; k < LL; ++k) xv += sc[k] * vb[k * DD + t];
  for (int i = 0; i < 26; ++i) xv += whd[i] * hour_emb[i * DD + t];
  for (int i = 0; i < 8; ++i)  xv += whd[26 + i] * day_emb[i * DD + t];
  xv += src[(b * LL + j) * DD + t];   // residual
  // LayerNorm
  const float s1 = wredSum(xv);
  const float s2 = wredSum(xv * xv);
  if ((t & 63) == 0) { red[t >> 6] = s1; red[4 + (t >> 6)] = s2; }
  __syncthreads();
  const float mean = (red[0] + red[1] + red[2] + red[3]) * (1.f / DD);
  const float var  = (red[4] + red[5] + red[6] + red[7]) * (1.f / DD) - mean * mean;
  X[(b * LL + j) * DD + t] = (xv - mean) * rsqrtf(var + 1e-5f) * g11[t] + b11[t];
}

// ---------------------------------------------------------------------------
// Kernel 3: FFN (relu(x@W1^T+b1)@W2^T+b2) + residual + LayerNorm.
// grid 32 row-tiles of 16, 256 threads.
// ---------------------------------------------------------------------------
__global__ __launch_bounds__(256) void k_ffn(
    const float* __restrict__ X,
    const float* __restrict__ wf1, const float* __restrict__ bf1,
    const float* __restrict__ wf2, const float* __restrict__ bf2,
    const float* __restrict__ g12, const float* __restrict__ b12,
    float* __restrict__ F)
{
  __shared__ float xs[16][DD];
  __shared__ float hs[16][DD];
  __shared__ float redsum[16][4];
  __shared__ float redsq[16][4];
  const int t = threadIdx.x;
  const int r0 = blockIdx.x * 16;
  for (int i = t; i < 16 * DD; i += 256) xs[i >> 8][i & 255] = X[r0 * DD + i];
  __syncthreads();
  float acc[16];
  const float b1 = bf1[t];
#pragma unroll
  for (int r = 0; r < 16; ++r) acc[r] = b1;
  for (int e = 0; e < DD; e += 4) {
    const float4 w4 = *(const float4*)(wf1 + t * DD + e);
#pragma unroll
    for (int r = 0; r < 16; ++r) acc[r] += dot4f(w4, *(const float4*)&xs[r][e]);
  }
#pragma unroll
  for (int r = 0; r < 16; ++r) hs[r][t] = fmaxf(acc[r], 0.f);
  __syncthreads();
  const float b2 = bf2[t];
#pragma unroll
  for (int r = 0; r < 16; ++r) acc[r] = b2;
  for (int e = 0; e < DD; e += 4) {
    const float4 w4 = *(const float4*)(wf2 + t * DD + e);
#pragma unroll
    for (int r = 0; r < 16; ++r) acc[r] += dot4f(w4, *(const float4*)&hs[r][e]);
  }
  const float g = g12[t], bb = b12[t];
#pragma unroll
  for (int r = 0; r < 16; ++r) {
    const float y = acc[r] + xs[r][t];   // residual
    acc[r] = y;
    const float s1 = wredSum(y);
    const float s2 = wredSum(y * y);
    if ((t & 63) == 0) { redsum[r][t >> 6] = s1; redsq[r][t >> 6] = s2; }
  }
  __syncthreads();
#pragma unroll
  for (int r = 0; r < 16; ++r) {
    const float mean = (redsum[r][0] + redsum[r][1] + redsum[r][2] + redsum[r][3]) * (1.f / DD);
    const float var  = (redsq[r][0] + redsq[r][1] + redsq[r][2] + redsq[r][3]) * (1.f / DD) - mean * mean;
    F[(r0 + r) * DD + t] = (acc[r] - mean) * rsqrtf(var + 1e-5f) * g + bb;
  }
}

// ---------------------------------------------------------------------------
// Kernel 4: per (b,j): prefix-sum of f over k<=j + label-embedding count
// histogram sums, scaled by 1/(j+1). grid 512, 256 threads.
// ---------------------------------------------------------------------------
__global__ __launch_bounds__(256) void k_prep(
    const float* __restrict__ F,
    const float* __restrict__ hour_emb, const float* __restrict__ day_emb,
    const int* __restrict__ seq_lens, const int* __restrict__ ts_g,
    const int* __restrict__ lts_g,
    float* __restrict__ GS)
{
  const int b = blockIdx.x >> 7;
  const int j = blockIdx.x & (LL - 1);
  const int t = threadIdx.x;
  __shared__ float cnt[34];
  if (t < 34) cnt[t] = 0.f;
  __syncthreads();
  const int len = seq_lens[b];
  if (t <= j && j < len) {          // valid region; no j==b override for labels
    const int ldiff = lts_g[b * LL + j] - ts_g[b * LL + t];   // >= 0
    const int lh = (ldiff % TU_C) / TB_C + 2;
    const int ld = min(ldiff / TU_C + 1, 7);
    atomicAdd(&cnt[lh], 1.f);
    atomicAdd(&cnt[26 + ld], 1.f);
  }
  __syncthreads();
  float sv = 0.f;
  for (int i = 0; i < 26; ++i) sv += cnt[i] * hour_emb[i * DD + t];
  for (int i = 0; i < 8; ++i)  sv += cnt[26 + i] * day_emb[i * DD + t];
  float gacc = 0.f;
  const float* fb = F + b * LL * DD;
  for (int k = 0; k <= j; ++k) gacc += fb[k * DD + t];   // pooling sums ALL k<=j
  GS[(b * LL + j) * DD + t] = (gacc + sv) / (float)(j + 1);
}

// ---------------------------------------------------------------------------
// Kernel 5: decoder GEMM pooled[r,p] = GS[r,:]·wdec[p,:] + bdec[p].
// grid (4 col-tiles of 256, 32 row-tiles of 16), 256 threads.
// ---------------------------------------------------------------------------
__global__ __launch_bounds__(256) void k_dec(
    const float* __restrict__ GS, const float* __restrict__ wdec,
    const float* __restrict__ bdec, float* __restrict__ out)
{
  __shared__ float xs[16][DD];
  const int t = threadIdx.x;
  const int r0 = blockIdx.y * 16;
  const int p = blockIdx.x * 256 + t;
  for (int i = t; i < 16 * DD; i += 256) xs[i >> 8][i & 255] = GS[r0 * DD + i];
  __syncthreads();
  float acc[16];
  const float bv_ = bdec[p];
#pragma unroll
  for (int r = 0; r < 16; ++r) acc[r] = bv_;
  for (int e = 0; e < DD; e += 4) {
    const float4 w4 = *(const float4*)(wdec + p * DD + e);
#pragma unroll
    for (int r = 0; r < 16; ++r) acc[r] += dot4f(w4, *(const float4*)&xs[r][e]);
  }
#pragma unroll
  for (int r = 0; r < 16; ++r) out[(r0 + r) * PP + p] = acc[r];
}

extern "C" void kernel_launch(void* const* d_in, const int* in_sizes, int n_in,
                              void* d_out, int out_size, void* d_ws, size_t ws_size,
                              hipStream_t stream)
{
  (void)in_sizes; (void)n_in; (void)out_size; (void)ws_size;
  const float* src      = (const float*)d_in[0];
  const float* hour_emb = (const float*)d_in[1];
  const float* day_emb  = (const float*)d_in[2];
  const float* wq  = (const float*)d_in[3];
  const float* bq  = (const float*)d_in[4];
  const float* wk  = (const float*)d_in[5];
  const float* bk  = (const float*)d_in[6];
  const float* wv  = (const float*)d_in[7];
  const float* bv  = (const float*)d_in[8];
  const float* g11 = (const float*)d_in[9];
  const float* b11 = (const float*)d_in[10];
  const float* wf1 = (const float*)d_in[11];
  const float* bf1 = (const float*)d_in[12];
  const float* wf2 = (const float*)d_in[13];
  const float* bf2 = (const float*)d_in[14];
  const float* g12 = (const float*)d_in[15];
  const float* b12 = (const float*)d_in[16];
  const float* wdec = (const float*)d_in[17];
  const float* bdec = (const float*)d_in[18];
  const int* seq_lens = (const int*)d_in[19];
  const int* ts  = (const int*)d_in[20];
  const int* lts = (const int*)d_in[21];
  float* out = (float*)d_out;
  float* ws = (float*)d_ws;
  float* Q  = ws;
  float* K  = ws + 131072;
  float* V  = ws + 262144;
  float* X  = ws + 393216;
  float* F  = ws + 524288;
  float* GS = ws + 655360;

  k_qkv<<<dim3(32, 3), 256, 0, stream>>>(src, wq, bq, wk, bk, wv, bv, Q, K, V);
  k_attn<<<512, 256, 0, stream>>>(Q, K, V, src, hour_emb, day_emb, seq_lens, ts, g11, b11, X);
  k_ffn<<<32, 256, 0, stream>>>(X, wf1, bf1, wf2, bf2, g12, b12, F);
  k_prep<<<512, 256, 0, stream>>>(F, hour_emb, day_emb, seq_lens, ts, lts, GS);
  k_dec<<<dim3(4, 32), 256, 0, stream>>>(GS, wdec, bdec, out);
}

// Round 3
// 128.980 us; speedup vs baseline: 1.1836x; 1.1836x over previous
//
#include <hip/hip_runtime.h>
#include <hip/hip_bf16.h>

#define LL 128
#define DD 256
#define PP 1024
#define TU_C 86400
#define TB_C 3600
#define NEGF -4294967296.0f   // float(-2**32+1) rounds to -2^32

// NOTE: parameter names must not collide with .x/.y/.z/.w member tokens
#define FMA4(ACC_, SS_, WW_) { (ACC_).x += (SS_)*(WW_).x; (ACC_).y += (SS_)*(WW_).y; (ACC_).z += (SS_)*(WW_).z; (ACC_).w += (SS_)*(WW_).w; }

__device__ __forceinline__ float wredSum(float v) {
#pragma unroll
  for (int o = 32; o; o >>= 1) v += __shfl_xor(v, o);
  return v;
}
__device__ __forceinline__ float wredMax(float v) {
#pragma unroll
  for (int o = 32; o; o >>= 1) v = fmaxf(v, __shfl_xor(v, o));
  return v;
}
__device__ __forceinline__ float dot4f(const float4 a, const float4 b) {
  return a.x * b.x + a.y * b.y + a.z * b.z + a.w * b.w;
}

// ---------------------------------------------------------------------------
// Kernel 0: transpose all weight matrices so GEMMs read coalesced.
// WT layout in ws: WTq 0, WTk 65536, WTv 131072, WTf1 196608, WTf2 262144,
// WTdec 327680 (size 262144). 32x32 tiles, 576 blocks.
// ---------------------------------------------------------------------------
__global__ __launch_bounds__(256) void k_wt(
    const float* __restrict__ wq, const float* __restrict__ wk,
    const float* __restrict__ wv, const float* __restrict__ wf1,
    const float* __restrict__ wf2, const float* __restrict__ wdec,
    float* __restrict__ wt)
{
  __shared__ float s[32][33];
  const int tile = blockIdx.x;
  const float* src; float* dst; int R, m;
  if (tile < 320) {
    const int mi = tile >> 6; m = tile & 63;
    src = (mi == 0) ? wq : (mi == 1) ? wk : (mi == 2) ? wv : (mi == 3) ? wf1 : wf2;
    dst = wt + mi * 65536; R = 256;
  } else {
    m = tile - 320; src = wdec; dst = wt + 327680; R = 1024;
  }
  const int sr = (m >> 3) * 32, sc0 = (m & 7) * 32;
  const int tx = threadIdx.x & 31, ty = threadIdx.x >> 5;
#pragma unroll
  for (int i = 0; i < 4; ++i)
    s[ty + 8 * i][tx] = src[(sr + ty + 8 * i) * 256 + sc0 + tx];
  __syncthreads();
#pragma unroll
  for (int i = 0; i < 4; ++i)
    dst[(sc0 + ty + 8 * i) * R + sr + tx] = s[tx][ty + 8 * i];
}

// ---------------------------------------------------------------------------
// Shared GEMM inner: 2 rows x 4 cols per thread, x from LDS, WT coalesced.
// ---------------------------------------------------------------------------
__device__ __forceinline__ void gemm2x4(const float (*xs)[DD], int rA, int rB,
                                        const float* __restrict__ wp_base, int cg,
                                        float4& a0, float4& a1)
{
  for (int e = 0; e < DD; e += 4) {
    const float4 xa = *(const float4*)&xs[rA][e];
    const float4 xb = *(const float4*)&xs[rB][e];
    const float* wp = wp_base + e * DD + 4 * cg;
    const float4 w0 = *(const float4*)(wp);
    const float4 w1 = *(const float4*)(wp + DD);
    const float4 w2 = *(const float4*)(wp + 2 * DD);
    const float4 w3 = *(const float4*)(wp + 3 * DD);
    FMA4(a0, xa.x, w0) FMA4(a0, xa.y, w1) FMA4(a0, xa.z, w2) FMA4(a0, xa.w, w3)
    FMA4(a1, xb.x, w0) FMA4(a1, xb.y, w1) FMA4(a1, xb.z, w2) FMA4(a1, xb.w, w3)
  }
}

// ---------------------------------------------------------------------------
// Kernel 1: Q/K/V projections. grid (64 row-tiles of 8, 3), 256 threads.
// K is written TRANSPOSED per batch: KT[b][e][k], k coalesced for attention.
// ---------------------------------------------------------------------------
__global__ __launch_bounds__(256) void k_qkv(
    const float* __restrict__ src, const float* __restrict__ wt,
    const float* __restrict__ bq, const float* __restrict__ bk,
    const float* __restrict__ bv,
    float* __restrict__ Q, float* __restrict__ KT, float* __restrict__ V)
{
  __shared__ float xs[8][DD];
  const int t = threadIdx.x, cg = t & 63, rg = t >> 6;
  const int r0 = blockIdx.x * 8;
  const int mat = blockIdx.y;
  const float* w = wt + mat * 65536;
  const float* bi = (mat == 0) ? bq : (mat == 1) ? bk : bv;
  for (int i = t; i < 8 * DD; i += 256) xs[i >> 8][i & 255] = src[r0 * DD + i];
  __syncthreads();
  const float4 bias4 = *(const float4*)(bi + 4 * cg);
  float4 a0 = bias4, a1 = bias4;
  gemm2x4(xs, 2 * rg, 2 * rg + 1, w, cg, a0, a1);
  const int rA = r0 + 2 * rg, rB = rA + 1;
  if (mat == 1) {
    const int bA = rA >> 7, kA = rA & 127;
    const float vA[4] = {a0.x, a0.y, a0.z, a0.w};
    const float vB[4] = {a1.x, a1.y, a1.z, a1.w};
#pragma unroll
    for (int c = 0; c < 4; ++c) {
      KT[bA * 32768 + (4 * cg + c) * 128 + kA]     = vA[c];
      KT[bA * 32768 + (4 * cg + c) * 128 + kA + 1] = vB[c];  // rA even -> rB same batch
    }
  } else {
    float* o = (mat == 0) ? Q : V;
    *(float4*)(o + rA * DD + 4 * cg) = a0;
    *(float4*)(o + rB * DD + 4 * cg) = a1;
  }
}

// ---------------------------------------------------------------------------
// Kernel 2: fused attention row. grid 512 = (b,j), 256 threads.
// Waves 0-1: coalesced K-dot via KT. Wave 3: 34 embedding dots (overlapped).
// ---------------------------------------------------------------------------
__global__ __launch_bounds__(256) void k_attn(
    const float* __restrict__ Q, const float* __restrict__ KT,
    const float* __restrict__ Vm, const float* __restrict__ src,
    const float* __restrict__ hour_emb, const float* __restrict__ day_emb,
    const int* __restrict__ seq_lens, const int* __restrict__ ts_g,
    const float* __restrict__ g11, const float* __restrict__ b11,
    float* __restrict__ X)
{
  const int b = blockIdx.x >> 7;
  const int j = blockIdx.x & (LL - 1);
  const int t = threadIdx.x;
  __shared__ float qrow[DD];
  __shared__ float sc[LL];
  __shared__ float qhd[34];   // qh[0..25], qd[26..33]
  __shared__ float whd[34];   // weighted histograms
  __shared__ float red[8];
  qrow[t] = Q[(b * LL + j) * DD + t];
  if (t < 34) whd[t] = 0.f;
  __syncthreads();
  float kdot = 0.f;
  if (t < LL) {
    const float* ktb = KT + b * 32768;
    for (int e = 0; e < DD; e += 4) {
      const float4 q4 = *(const float4*)&qrow[e];
      const float* kp = ktb + e * 128 + t;
      kdot += q4.x * kp[0] + q4.y * kp[128] + q4.z * kp[256] + q4.w * kp[384];
    }
  } else if (t >= 192 && t < 226) {
    const int i = t - 192;
    const float* emb = (i < 26) ? (hour_emb + i * DD) : (day_emb + (i - 26) * DD);
    float a = 0.f;
    for (int e = 0; e < DD; e += 4)
      a += dot4f(*(const float4*)&qrow[e], *(const float4*)(emb + e));
    qhd[i] = a;
  }
  const int len = seq_lens[b];
  const int* ts = ts_g + b * LL;
  const int tj = ts[j];
  __syncthreads();  // qhd ready
  int hidx = 0, didx = 0;
  float s = NEGF;
  const bool valid = (t < LL) && (j < len) && (t <= j);
  if (valid) {
    const int diff = tj - ts[t];                       // >= 0 (ts sorted, t<=j)
    hidx = (j == b) ? 1 : ((diff % TU_C) / TB_C + 2);  // faithful j==b bug
    didx = min(diff / TU_C + 1, 7);
    s = (kdot + qhd[hidx] + qhd[26 + didx]) * 0.0625f; // /sqrt(256)
  }
  // softmax over k=0..127 (all-NEG rows -> uniform 1/128, matching reference)
  float mv = (t < LL) ? s : -3.4e38f;
  mv = wredMax(mv);
  if ((t & 63) == 0) red[t >> 6] = mv;
  __syncthreads();
  const float m = fmaxf(fmaxf(red[0], red[1]), fmaxf(red[2], red[3]));
  const float p = (t < LL) ? expf(s - m) : 0.f;
  const float svr = wredSum(p);
  if ((t & 63) == 0) red[4 + (t >> 6)] = svr;
  __syncthreads();
  const float Z = red[4] + red[5] + red[6] + red[7];
  if (t < LL) {
    const float aw = p / Z;
    sc[t] = aw;
    atomicAdd(&whd[hidx], aw);       // idx 0 -> zero embedding row: harmless
    atomicAdd(&whd[26 + didx], aw);
  }
  __syncthreads();
  // x[d] = sum_k aw[k] V[k,d] + histogram-weighted embedding rows
  const float* vb = Vm + b * LL * DD;
  float xv = 0.f;
  for (int k = 0; k < LL; ++k) xv += sc[k] * vb[k * DD + t];
  for (int i = 0; i < 26; ++i) xv += whd[i] * hour_emb[i * DD + t];
  for (int i = 0; i < 8; ++i)  xv += whd[26 + i] * day_emb[i * DD + t];
  xv += src[(b * LL + j) * DD + t];   // residual
  const float s1 = wredSum(xv);
  const float s2 = wredSum(xv * xv);
  if ((t & 63) == 0) { red[t >> 6] = s1; red[4 + (t >> 6)] = s2; }
  __syncthreads();
  const float mean = (red[0] + red[1] + red[2] + red[3]) * (1.f / DD);
  const float var  = (red[4] + red[5] + red[6] + red[7]) * (1.f / DD) - mean * mean;
  X[(b * LL + j) * DD + t] = (xv - mean) * rsqrtf(var + 1e-5f) * g11[t] + b11[t];
}

// ---------------------------------------------------------------------------
// Kernel 3a: H = relu(X @ W1^T + b1). grid 64 row-tiles of 8, 256 threads.
// ---------------------------------------------------------------------------
__global__ __launch_bounds__(256) void k_ffn1(
    const float* __restrict__ X, const float* __restrict__ wt1,
    const float* __restrict__ bf1, float* __restrict__ H)
{
  __shared__ float xs[8][DD];
  const int t = threadIdx.x, cg = t & 63, rg = t >> 6;
  const int r0 = blockIdx.x * 8;
  for (int i = t; i < 8 * DD; i += 256) xs[i >> 8][i & 255] = X[r0 * DD + i];
  __syncthreads();
  const float4 bias4 = *(const float4*)(bf1 + 4 * cg);
  float4 a0 = bias4, a1 = bias4;
  gemm2x4(xs, 2 * rg, 2 * rg + 1, wt1, cg, a0, a1);
  const int rA = r0 + 2 * rg, rB = rA + 1;
  float4 h0, h1;
  h0.x = fmaxf(a0.x, 0.f); h0.y = fmaxf(a0.y, 0.f); h0.z = fmaxf(a0.z, 0.f); h0.w = fmaxf(a0.w, 0.f);
  h1.x = fmaxf(a1.x, 0.f); h1.y = fmaxf(a1.y, 0.f); h1.z = fmaxf(a1.z, 0.f); h1.w = fmaxf(a1.w, 0.f);
  *(float4*)(H + rA * DD + 4 * cg) = h0;
  *(float4*)(H + rB * DD + 4 * cg) = h1;
}

// ---------------------------------------------------------------------------
// Kernel 3b: F = LN(H @ W2^T + b2 + X). Wave owns 2 full rows -> in-wave LN.
// ---------------------------------------------------------------------------
__global__ __launch_bounds__(256) void k_ffn2(
    const float* __restrict__ H, const float* __restrict__ Xg,
    const float* __restrict__ wt2, const float* __restrict__ bf2,
    const float* __restrict__ g12, const float* __restrict__ b12,
    float* __restrict__ F)
{
  __shared__ float hs[8][DD];
  const int t = threadIdx.x, cg = t & 63, rg = t >> 6;
  const int r0 = blockIdx.x * 8;
  for (int i = t; i < 8 * DD; i += 256) hs[i >> 8][i & 255] = H[r0 * DD + i];
  __syncthreads();
  const float4 bias4 = *(const float4*)(bf2 + 4 * cg);
  float4 a0 = bias4, a1 = bias4;
  gemm2x4(hs, 2 * rg, 2 * rg + 1, wt2, cg, a0, a1);
  const int rA = r0 + 2 * rg, rB = rA + 1;
  const float4 xr0 = *(const float4*)(Xg + rA * DD + 4 * cg);
  const float4 xr1 = *(const float4*)(Xg + rB * DD + 4 * cg);
  a0.x += xr0.x; a0.y += xr0.y; a0.z += xr0.z; a0.w += xr0.w;
  a1.x += xr1.x; a1.y += xr1.y; a1.z += xr1.z; a1.w += xr1.w;
  const float s0 = wredSum(a0.x + a0.y + a0.z + a0.w);
  const float q0 = wredSum(a0.x*a0.x + a0.y*a0.y + a0.z*a0.z + a0.w*a0.w);
  const float s1 = wredSum(a1.x + a1.y + a1.z + a1.w);
  const float q1 = wredSum(a1.x*a1.x + a1.y*a1.y + a1.z*a1.z + a1.w*a1.w);
  const float m0 = s0 * (1.f / DD), m1 = s1 * (1.f / DD);
  const float rs0 = rsqrtf(q0 * (1.f / DD) - m0 * m0 + 1e-5f);
  const float rs1 = rsqrtf(q1 * (1.f / DD) - m1 * m1 + 1e-5f);
  const float4 g4 = *(const float4*)(g12 + 4 * cg);
  const float4 b4 = *(const float4*)(b12 + 4 * cg);
  float4 o0, o1;
  o0.x = (a0.x - m0) * rs0 * g4.x + b4.x; o0.y = (a0.y - m0) * rs0 * g4.y + b4.y;
  o0.z = (a0.z - m0) * rs0 * g4.z + b4.z; o0.w = (a0.w - m0) * rs0 * g4.w + b4.w;
  o1.x = (a1.x - m1) * rs1 * g4.x + b4.x; o1.y = (a1.y - m1) * rs1 * g4.y + b4.y;
  o1.z = (a1.z - m1) * rs1 * g4.z + b4.z; o1.w = (a1.w - m1) * rs1 * g4.w + b4.w;
  *(float4*)(F + rA * DD + 4 * cg) = o0;
  *(float4*)(F + rB * DD + 4 * cg) = o1;
}

// ---------------------------------------------------------------------------
// Kernel 4: per (b,j): prefix-sum of f over k<=j + label-embedding counts,
// scaled by 1/(j+1). grid 512, 256 threads.
// ---------------------------------------------------------------------------
__global__ __launch_bounds__(256) void k_prep(
    const float* __restrict__ F,
    const float* __restrict__ hour_emb, const float* __restrict__ day_emb,
    const int* __restrict__ seq_lens, const int* __restrict__ ts_g,
    const int* __restrict__ lts_g,
    float* __restrict__ GS)
{
  const int b = blockIdx.x >> 7;
  const int j = blockIdx.x & (LL - 1);
  const int t = threadIdx.x;
  __shared__ float cnt[34];
  if (t < 34) cnt[t] = 0.f;
  __syncthreads();
  const int len = seq_lens[b];
  if (t <= j && j < len) {          // valid region; no j==b override for labels
    const int ldiff = lts_g[b * LL + j] - ts_g[b * LL + t];   // >= 0
    const int lh = (ldiff % TU_C) / TB_C + 2;
    const int ld = min(ldiff / TU_C + 1, 7);
    atomicAdd(&cnt[lh], 1.f);
    atomicAdd(&cnt[26 + ld], 1.f);
  }
  __syncthreads();
  float sv = 0.f;
  for (int i = 0; i < 26; ++i) sv += cnt[i] * hour_emb[i * DD + t];
  for (int i = 0; i < 8; ++i)  sv += cnt[26 + i] * day_emb[i * DD + t];
  float gacc = 0.f;
  const float* fb = F + b * LL * DD;
  for (int k = 0; k <= j; ++k) gacc += fb[k * DD + t];   // pooling sums ALL k<=j
  GS[(b * LL + j) * DD + t] = (gacc + sv) / (float)(j + 1);
}

// ---------------------------------------------------------------------------
// Kernel 5: decoder GEMM pooled = GS @ WTdec + bdec. 4 rows x 4 cols/thread.
// grid 128 (row-tiles of 4), 256 threads cover all 1024 cols.
// ---------------------------------------------------------------------------
__global__ __launch_bounds__(256) void k_dec(
    const float* __restrict__ GS, const float* __restrict__ wtd,
    const float* __restrict__ bdec, float* __restrict__ out)
{
  __shared__ float xs[4][DD];
  const int t = threadIdx.x;
  const int r0 = blockIdx.x * 4;
  for (int i = t; i < 4 * DD; i += 256) xs[i >> 8][i & 255] = GS[r0 * DD + i];
  __syncthreads();
  const float4 bias4 = *(const float4*)(bdec + 4 * t);
  float4 a0 = bias4, a1 = bias4, a2 = bias4, a3 = bias4;
  for (int e = 0; e < DD; e += 4) {
    const float4 x0 = *(const float4*)&xs[0][e];
    const float4 x1 = *(const float4*)&xs[1][e];
    const float4 x2 = *(const float4*)&xs[2][e];
    const float4 x3 = *(const float4*)&xs[3][e];
    const float* wp = wtd + e * PP + 4 * t;
    const float4 w0 = *(const float4*)(wp);
    const float4 w1 = *(const float4*)(wp + PP);
    const float4 w2 = *(const float4*)(wp + 2 * PP);
    const float4 w3 = *(const float4*)(wp + 3 * PP);
    FMA4(a0, x0.x, w0) FMA4(a0, x0.y, w1) FMA4(a0, x0.z, w2) FMA4(a0, x0.w, w3)
    FMA4(a1, x1.x, w0) FMA4(a1, x1.y, w1) FMA4(a1, x1.z, w2) FMA4(a1, x1.w, w3)
    FMA4(a2, x2.x, w0) FMA4(a2, x2.y, w1) FMA4(a2, x2.z, w2) FMA4(a2, x2.w, w3)
    FMA4(a3, x3.x, w0) FMA4(a3, x3.y, w1) FMA4(a3, x3.z, w2) FMA4(a3, x3.w, w3)
  }
  *(float4*)(out + (r0 + 0) * PP + 4 * t) = a0;
  *(float4*)(out + (r0 + 1) * PP + 4 * t) = a1;
  *(float4*)(out + (r0 + 2) * PP + 4 * t) = a2;
  *(float4*)(out + (r0 + 3) * PP + 4 * t) = a3;
}

extern "C" void kernel_launch(void* const* d_in, const int* in_sizes, int n_in,
                              void* d_out, int out_size, void* d_ws, size_t ws_size,
                              hipStream_t stream)
{
  (void)in_sizes; (void)n_in; (void)out_size; (void)ws_size;
  const float* src      = (const float*)d_in[0];
  const float* hour_emb = (const float*)d_in[1];
  const float* day_emb  = (const float*)d_in[2];
  const float* wq  = (const float*)d_in[3];
  const float* bq  = (const float*)d_in[4];
  const float* wk  = (const float*)d_in[5];
  const float* bk  = (const float*)d_in[6];
  const float* wv  = (const float*)d_in[7];
  const float* bv  = (const float*)d_in[8];
  const float* g11 = (const float*)d_in[9];
  const float* b11 = (const float*)d_in[10];
  const float* wf1 = (const float*)d_in[11];
  const float* bf1 = (const float*)d_in[12];
  const float* wf2 = (const float*)d_in[13];
  const float* bf2 = (const float*)d_in[14];
  const float* g12 = (const float*)d_in[15];
  const float* b12 = (const float*)d_in[16];
  const float* wdec = (const float*)d_in[17];
  const float* bdec = (const float*)d_in[18];
  const int* seq_lens = (const int*)d_in[19];
  const int* ts  = (const int*)d_in[20];
  const int* lts = (const int*)d_in[21];
  float* out = (float*)d_out;
  float* ws = (float*)d_ws;
  // ws layout (floats):
  float* WT   = ws;                 // 0      .. 589824  (5x65536 + 262144)
  float* Q    = ws + 589824;        // 131072
  float* KT   = ws + 720896;        // 131072 (4 batches x [256e][128k])
  float* V    = ws + 851968;        // 131072
  float* X    = ws + 983040;        // 131072
  float* H    = ws + 1114112;       // 131072
  float* F    = ws + 1245184;       // 131072
  float* GS   = ws + 1376256;       // 131072 -> end 1507328 floats = 6.03 MB

  k_wt  <<<576, 256, 0, stream>>>(wq, wk, wv, wf1, wf2, wdec, WT);
  k_qkv <<<dim3(64, 3), 256, 0, stream>>>(src, WT, bq, bk, bv, Q, KT, V);
  k_attn<<<512, 256, 0, stream>>>(Q, KT, V, src, hour_emb, day_emb, seq_lens, ts, g11, b11, X);
  k_ffn1<<<64, 256, 0, stream>>>(X, WT + 196608, bf1, H);
  k_ffn2<<<64, 256, 0, stream>>>(H, X, WT + 262144, bf2, g12, b12, F);
  k_prep<<<512, 256, 0, stream>>>(F, hour_emb, day_emb, seq_lens, ts, lts, GS);
  k_dec <<<128, 256, 0, stream>>>(GS, WT + 327680, bdec, out);
}